// Round 8
// baseline (290.338 us; speedup 1.0000x reference)
//
#include <hip/hip_runtime.h>
#include <math.h>

// Problem constants: D=64 dialogues, L=64, DIM=512, G=256
// m = 3*L = 192 nodes/hyperedges per dialogue, k = 12, N = D*L = 4096
#define NDIAL 64
#define M3    192
#define DIMF  512
#define GDIM  256
#define NROW  4096
#define TOPK  12
#define INV_TAU (1.0f/0.07f)

typedef __attribute__((ext_vector_type(8))) short bf16x8;
typedef __attribute__((ext_vector_type(4))) float f32x4;
typedef __attribute__((ext_vector_type(8))) ushort us8;
typedef _Float16 f16x8 __attribute__((ext_vector_type(8)));
typedef _Float16 f16x4v __attribute__((ext_vector_type(4)));
typedef __attribute__((address_space(3))) ushort lds_us;
typedef const __attribute__((address_space(1))) ushort gm_us;

__device__ __forceinline__ ushort f2bf(float f) {
    unsigned u = __float_as_uint(f);
    unsigned r = (u + 0x7fff + ((u >> 16) & 1)) >> 16;   // RNE
    return (ushort)r;
}

// ---------------------------------------------------------------------------
// fp16 MFMA GEMM helper: block = 64 rows x (NW*64) cols, NW waves (wave w
// owns col block w). A: [M][K] row-major; B: "B^T layout" [N][K] row-major.
// C/D: row = fm*16 + qd*4 + rg, col = w*64 + fn*16 + l15.
// ---------------------------------------------------------------------------
template<int KD, int NW>
__device__ __forceinline__ void hgemm_bt(const _Float16* __restrict__ A, int lda,
                                         const _Float16* __restrict__ B, int ldb,
                                         f32x4 acc[4][4]) {
    __shared__ __align__(16) _Float16 As[64 * 40];
    __shared__ __align__(16) _Float16 Bs[NW * 64 * 40];
    const int tid = threadIdx.x;
    const int lane = tid & 63, w = tid >> 6;
    const int qd = lane >> 4, l15 = lane & 15;

#pragma unroll
    for (int fm = 0; fm < 4; fm++)
#pragma unroll
        for (int fn = 0; fn < 4; fn++)
            acc[fm][fn] = (f32x4){0.f, 0.f, 0.f, 0.f};

    for (int k0 = 0; k0 < KD; k0 += 32) {
        for (int f = tid; f < 256; f += NW * 64) {
            int row = f >> 2, c8 = f & 3;
            *(float4*)&As[row * 40 + c8 * 8] =
                *(const float4*)&A[(size_t)row * lda + k0 + c8 * 8];
        }
#pragma unroll
        for (int i = 0; i < 4; i++) {
            int f = tid + i * NW * 64;
            int row = f >> 2, c8 = f & 3;
            *(float4*)&Bs[row * 40 + c8 * 8] =
                *(const float4*)&B[(size_t)row * ldb + k0 + c8 * 8];
        }
        __syncthreads();
        f16x8 af[4], bfr[4];
#pragma unroll
        for (int fm = 0; fm < 4; fm++)
            af[fm] = *(const f16x8*)&As[(fm * 16 + l15) * 40 + qd * 8];
#pragma unroll
        for (int fn = 0; fn < 4; fn++)
            bfr[fn] = *(const f16x8*)&Bs[(w * 64 + fn * 16 + l15) * 40 + qd * 8];
#pragma unroll
        for (int fm = 0; fm < 4; fm++)
#pragma unroll
            for (int fn = 0; fn < 4; fn++)
                acc[fm][fn] = __builtin_amdgcn_mfma_f32_16x16x32_f16(
                    af[fm], bfr[fn], acc[fm][fn], 0, 0, 0);
        __syncthreads();
    }
}

__device__ __forceinline__ const float* node_ptr(const float* t, const float* a,
                                                 const float* v, int d, int j) {
    int mod = j >> 6, i = j & 63;
    const float* base = (mod == 0) ? t : (mod == 1) ? a : v;
    return base + (size_t)(d * 64 + i) * DIMF;
}

// ---- KPREP: fp16 hi/lo feat, featT, Wfch, WhT, sq, zero-init ----
// blocks: [0,6144) feat hi/lo; [6144,6272) Wfch; [6272,6336) WhT;
// [6336,9408) sq; [9408,9456) zero rs/cs/degV; [9456,11760) zero HbT+HbTd;
// [11760,13296) featT transpose tiles
__global__ void kprep(const float* __restrict__ t, const float* __restrict__ a,
                      const float* __restrict__ v, const float* __restrict__ Wfc,
                      const float* __restrict__ Wh, _Float16* __restrict__ feath,
                      _Float16* __restrict__ featl, _Float16* __restrict__ featT,
                      _Float16* __restrict__ Wfch, _Float16* __restrict__ WhT,
                      float* __restrict__ sq, float* __restrict__ rs,
                      float* __restrict__ cs, float* __restrict__ degV,
                      _Float16* __restrict__ HbT) {
    int b = blockIdx.x, tid = threadIdx.x;
    if (b < 6144) {
        int e = (b * 256 + tid) * 4;
        int d = e / (M3 * DIMF);
        int rem = e % (M3 * DIMF);
        int n = rem / DIMF, kk = rem % DIMF;
        int mod = n >> 6, i = n & 63;
        const float* src = ((mod == 0) ? t : (mod == 1) ? a : v)
                           + (size_t)(d * 64 + i) * DIMF + kk;
        float4 x = *(const float4*)src;
        f16x4v h = {(_Float16)x.x, (_Float16)x.y, (_Float16)x.z, (_Float16)x.w};
        f16x4v l = {(_Float16)(x.x - (float)h.x), (_Float16)(x.y - (float)h.y),
                    (_Float16)(x.z - (float)h.z), (_Float16)(x.w - (float)h.w)};
        *(f16x4v*)&feath[e] = h;
        *(f16x4v*)&featl[e] = l;
    } else if (b < 6272) {
        int e = ((b - 6144) * 256 + tid) * 4;
        float4 x = *(const float4*)&Wfc[e];
        f16x4v o = {(_Float16)x.x, (_Float16)x.y, (_Float16)x.z, (_Float16)x.w};
        *(f16x4v*)&Wfch[e] = o;
    } else if (b < 6336) {
        int e = ((b - 6272) * 256 + tid) * 4;
        int go = e >> 8, g = e & 255;
        f16x4v o = {(_Float16)Wh[(size_t)(g + 0) * GDIM + go],
                    (_Float16)Wh[(size_t)(g + 1) * GDIM + go],
                    (_Float16)Wh[(size_t)(g + 2) * GDIM + go],
                    (_Float16)Wh[(size_t)(g + 3) * GDIM + go]};
        *(f16x4v*)&WhT[(size_t)go * GDIM + g] = o;
    } else if (b < 9408) {
        int lane = tid & 63, wv = tid >> 6;
        int n = (b - 6336) * 4 + wv;
        int d = n / M3, j = n % M3;
        const float4* s4 = (const float4*)node_ptr(t, a, v, d, j);
        float s = 0.f;
#pragma unroll
        for (int q = 0; q < 2; q++) {
            float4 x = s4[lane + q * 64];
            s += x.x * x.x + x.y * x.y + x.z * x.z + x.w * x.w;
        }
        for (int o = 32; o; o >>= 1) s += __shfl_down(s, o);
        if (lane == 0) sq[n] = s;
    } else if (b < 9456) {
        int i = (b - 9408) * 256 + tid;
        rs[i] = 0.f; cs[i] = 0.f; degV[i] = 0.f;
    } else if (b < 11760) {
        int i = (b - 9456) * 256 + tid;     // zero HbT + HbTd (contiguous)
        ulonglong2 z = {0ull, 0ull};
        *(ulonglong2*)&HbT[(size_t)i * 8] = z;
    } else {
        // featT[d][f][j]: transpose 64x64 tiles via LDS
        __shared__ _Float16 tl[64 * 72];
        int idx = b - 11760;
        int d = idx / 24, rem = idx % 24;
        int jb = rem / 8, fb = rem % 8;     // jb = modality band (64 nodes)
        const float* src = ((jb == 0) ? t : (jb == 1) ? a : v)
                           + (size_t)(d * 64) * DIMF + fb * 64;
#pragma unroll
        for (int it = 0; it < 4; it++) {
            int jj = (tid >> 4) + it * 16, ff = (tid & 15) * 4;
            float4 x = *(const float4*)&src[(size_t)jj * DIMF + ff];
            tl[jj * 72 + ff + 0] = (_Float16)x.x;
            tl[jj * 72 + ff + 1] = (_Float16)x.y;
            tl[jj * 72 + ff + 2] = (_Float16)x.z;
            tl[jj * 72 + ff + 3] = (_Float16)x.w;
        }
        __syncthreads();
        _Float16* dst = featT + (size_t)d * DIMF * M3 + (size_t)(fb * 64) * M3 + jb * 64;
#pragma unroll
        for (int it = 0; it < 4; it++) {
            int fr = (tid >> 4) + it * 16, jc = (tid & 15) * 4;
            f16x4v o = {tl[(jc + 0) * 72 + fr], tl[(jc + 1) * 72 + fr],
                        tl[(jc + 2) * 72 + fr], tl[(jc + 3) * 72 + fr]};
            *(f16x4v*)&dst[(size_t)fr * M3 + jc] = o;
        }
    }
}

// ---- KW: W2t = (Wfc@Wh)^T [256][512] fp16; b2 = Wh^T bfc + bh ----
__global__ void kW(const _Float16* __restrict__ WhT, const _Float16* __restrict__ Wfch,
                   const float* __restrict__ bfc, const float* __restrict__ bh,
                   const float* __restrict__ Wh, _Float16* __restrict__ W2t,
                   float* __restrict__ b2) {
    if (blockIdx.x == 8) {
        int go = threadIdx.x;
        float s = bh[go];
        for (int g = 0; g < GDIM; g++) s += bfc[g] * Wh[(size_t)g * GDIM + go];
        b2[go] = s;
        return;
    }
    int rb = blockIdx.x >> 1, cb = blockIdx.x & 1;
    f32x4 acc[4][4];
    hgemm_bt<GDIM, 4>(WhT + (size_t)rb * 64 * GDIM, GDIM,
                      Wfch + (size_t)cb * 256 * GDIM, GDIM, acc);
    int lane = threadIdx.x & 63, w = threadIdx.x >> 6;
    int qd = lane >> 4, l15 = lane & 15;
#pragma unroll
    for (int fm = 0; fm < 4; fm++)
#pragma unroll
        for (int rg = 0; rg < 4; rg++) {
            int go = rb * 64 + fm * 16 + qd * 4 + rg;
#pragma unroll
            for (int fn = 0; fn < 4; fn++) {
                int f = cb * 256 + w * 64 + fn * 16 + l15;
                W2t[(size_t)go * DIMF + f] = (_Float16)acc[fm][fn][rg];
            }
        }
}

// ---- K1: d2 via fp16-split MFMA Gram (hi*hi + hi*lo + lo*hi).
//      Residual error ~2e-5 (dropped lo*lo) ~= np fp32 noise; selection-safe. ----
__global__ __launch_bounds__(192) void k1_d2(const _Float16* __restrict__ feath,
                                             const _Float16* __restrict__ featl,
                                             const float* __restrict__ sq,
                                             float* __restrict__ d2) {
    __shared__ __align__(16) _Float16 Ah[64 * 40], Al[64 * 40];
    __shared__ __align__(16) _Float16 Bh[M3 * 40], Bl[M3 * 40];
    int rb = blockIdx.x, d = blockIdx.y;
    const _Float16* ah = feath + ((size_t)d * M3 + rb * 64) * DIMF;
    const _Float16* al = featl + ((size_t)d * M3 + rb * 64) * DIMF;
    const _Float16* bh = feath + (size_t)d * M3 * DIMF;
    const _Float16* bl = featl + (size_t)d * M3 * DIMF;
    const int tid = threadIdx.x;
    const int lane = tid & 63, w = tid >> 6;
    const int qd = lane >> 4, l15 = lane & 15;

    f32x4 acc[4][4] = {};
    for (int k0 = 0; k0 < DIMF; k0 += 32) {
        for (int f = tid; f < 256; f += 192) {
            int row = f >> 2, c8 = f & 3;
            *(float4*)&Ah[row * 40 + c8 * 8] =
                *(const float4*)&ah[(size_t)row * DIMF + k0 + c8 * 8];
            *(float4*)&Al[row * 40 + c8 * 8] =
                *(const float4*)&al[(size_t)row * DIMF + k0 + c8 * 8];
        }
#pragma unroll
        for (int i = 0; i < 4; i++) {
            int f = tid + i * 192;
            int row = f >> 2, c8 = f & 3;
            *(float4*)&Bh[row * 40 + c8 * 8] =
                *(const float4*)&bh[(size_t)row * DIMF + k0 + c8 * 8];
            *(float4*)&Bl[row * 40 + c8 * 8] =
                *(const float4*)&bl[(size_t)row * DIMF + k0 + c8 * 8];
        }
        __syncthreads();
        f16x8 afh[4], afl[4], bfh[4], bfl[4];
#pragma unroll
        for (int fm = 0; fm < 4; fm++) {
            afh[fm] = *(const f16x8*)&Ah[(fm * 16 + l15) * 40 + qd * 8];
            afl[fm] = *(const f16x8*)&Al[(fm * 16 + l15) * 40 + qd * 8];
        }
#pragma unroll
        for (int fn = 0; fn < 4; fn++) {
            bfh[fn] = *(const f16x8*)&Bh[(w * 64 + fn * 16 + l15) * 40 + qd * 8];
            bfl[fn] = *(const f16x8*)&Bl[(w * 64 + fn * 16 + l15) * 40 + qd * 8];
        }
#pragma unroll
        for (int fm = 0; fm < 4; fm++)
#pragma unroll
            for (int fn = 0; fn < 4; fn++) {
                acc[fm][fn] = __builtin_amdgcn_mfma_f32_16x16x32_f16(
                    afh[fm], bfh[fn], acc[fm][fn], 0, 0, 0);
                acc[fm][fn] = __builtin_amdgcn_mfma_f32_16x16x32_f16(
                    afh[fm], bfl[fn], acc[fm][fn], 0, 0, 0);
                acc[fm][fn] = __builtin_amdgcn_mfma_f32_16x16x32_f16(
                    afl[fm], bfh[fn], acc[fm][fn], 0, 0, 0);
            }
        __syncthreads();
    }
    const float* sqd = sq + d * M3;
    float* outp = d2 + (size_t)d * M3 * M3;
#pragma unroll
    for (int fm = 0; fm < 4; fm++)
#pragma unroll
        for (int rg = 0; rg < 4; rg++) {
            int il = rb * 64 + fm * 16 + qd * 4 + rg;
            float si = sqd[il];
#pragma unroll
            for (int fn = 0; fn < 4; fn++) {
                int jl = w * 64 + fn * 16 + l15;
                outp[(size_t)il * M3 + jl] =
                    fmaxf(si + sqd[jl] - 2.f * acc[fm][fn][rg], 0.f);
            }
        }
}

// ---- K2: wave-per-row top-12 -> scatter HbT (0/1) + HbTd (1/deg_e) + degV ----
__global__ void k2_topk(const float* __restrict__ d2, _Float16* __restrict__ HbT,
                        _Float16* __restrict__ HbTd, float* __restrict__ degV) {
    int lane = threadIdx.x & 63, wv = threadIdx.x >> 6;
    int r = blockIdx.x * 4 + wv;                 // 0..12287
    int d = r / M3, e = r % M3;
    const float* row = d2 + (size_t)r * M3;
    float w0 = row[lane], w1 = row[lane + 64], w2 = row[lane + 128];
    bool s0 = false, s1 = false, s2 = false;
#pragma unroll
    for (int it = 0; it < TOPK; it++) {
        float bv = w0; int bi = lane;
        if (w1 < bv) { bv = w1; bi = lane + 64; }
        if (w2 < bv) { bv = w2; bi = lane + 128; }
#pragma unroll
        for (int o = 1; o < 64; o <<= 1) {
            float ov = __shfl_xor(bv, o);
            int   oi = __shfl_xor(bi, o);
            if (ov < bv || (ov == bv && oi < bi)) { bv = ov; bi = oi; }
        }
        if (bi == lane)            { s0 = true; w0 = 3.4e38f; }
        else if (bi == lane + 64)  { s1 = true; w1 = 3.4e38f; }
        else if (bi == lane + 128) { s2 = true; w2 = 3.4e38f; }
    }
    int u = e / 3;
    if (lane == u) { s0 = true; s1 = true; s2 = true; }
    float cnt = (s0 ? 1.f : 0.f) + (s1 ? 1.f : 0.f) + (s2 ? 1.f : 0.f);
#pragma unroll
    for (int o = 1; o < 64; o <<= 1) cnt += __shfl_xor(cnt, o);
    _Float16 rde = (_Float16)(1.f / cnt);
    float* dv = degV + d * M3;
    _Float16* HT  = HbT  + (size_t)d * M3 * M3;
    _Float16* HTd = HbTd + (size_t)d * M3 * M3;
    if (s0) { atomicAdd(&dv[lane], 1.f);
              HT[(size_t)lane * M3 + e] = (_Float16)1.f;
              HTd[(size_t)lane * M3 + e] = rde; }
    if (s1) { atomicAdd(&dv[lane + 64], 1.f);
              HT[(size_t)(lane + 64) * M3 + e] = (_Float16)1.f;
              HTd[(size_t)(lane + 64) * M3 + e] = rde; }
    if (s2) { atomicAdd(&dv[lane + 128], 1.f);
              HT[(size_t)(lane + 128) * M3 + e] = (_Float16)1.f;
              HTd[(size_t)(lane + 128) * M3 + e] = rde; }
}

// ---- KM: S = H^T D_e^-1 H per dialogue. S[d][i][j] fp16 ----
__global__ __launch_bounds__(192) void kM(const _Float16* __restrict__ HbT,
                                          const _Float16* __restrict__ HbTd,
                                          _Float16* __restrict__ S) {
    int rb = blockIdx.x, d = blockIdx.y;
    f32x4 acc[4][4];
    hgemm_bt<M3, 3>(HbT + (size_t)d * M3 * M3 + (size_t)rb * 64 * M3, M3,
                    HbTd + (size_t)d * M3 * M3, M3, acc);
    int lane = threadIdx.x & 63, w = threadIdx.x >> 6;
    int qd = lane >> 4, l15 = lane & 15;
    _Float16* out = S + (size_t)d * M3 * M3;
#pragma unroll
    for (int fm = 0; fm < 4; fm++)
#pragma unroll
        for (int rg = 0; rg < 4; rg++) {
            int i = rb * 64 + fm * 16 + qd * 4 + rg;
#pragma unroll
            for (int fn = 0; fn < 4; fn++) {
                int j = w * 64 + fn * 16 + l15;
                out[(size_t)i * M3 + j] = (_Float16)acc[fm][fn][rg];
            }
        }
}

// ---- KZ: Z = (S @ feat) / deg_v.  Z[12288][512] fp16 ----
__global__ void kZ(const _Float16* __restrict__ S, const _Float16* __restrict__ featT,
                   const float* __restrict__ degV, _Float16* __restrict__ Z) {
    int rb = blockIdx.x % 3, cb = blockIdx.x / 3, d = blockIdx.y;
    f32x4 acc[4][4];
    hgemm_bt<M3, 4>(S + (size_t)d * M3 * M3 + (size_t)rb * 64 * M3, M3,
                    featT + (size_t)d * DIMF * M3 + (size_t)cb * 256 * M3, M3, acc);
    int lane = threadIdx.x & 63, w = threadIdx.x >> 6;
    int qd = lane >> 4, l15 = lane & 15;
#pragma unroll
    for (int fm = 0; fm < 4; fm++)
#pragma unroll
        for (int rg = 0; rg < 4; rg++) {
            int node = rb * 64 + fm * 16 + qd * 4 + rg;
            float idv = 1.f / degV[d * M3 + node];
            _Float16* zr = Z + ((size_t)d * M3 + node) * DIMF + cb * 256;
#pragma unroll
            for (int fn = 0; fn < 4; fn++) {
                int f = w * 64 + fn * 16 + l15;
                zr[f] = (_Float16)(acc[fm][fn][rg] * idv);
            }
        }
}

// ---- KO: out = relu(Z @ W2 + b2) -> fp32 d_out; fused normalize -> bf16 xnb ----
__global__ __launch_bounds__(256) void kO(const _Float16* __restrict__ Z,
                                          const _Float16* __restrict__ W2t,
                                          const float* __restrict__ b2,
                                          float* __restrict__ outp,
                                          ushort* __restrict__ xnb) {
    __shared__ float tile[64 * 256];
    __shared__ float ssq[64];
    int b = blockIdx.x, tid = threadIdx.x;
    if (tid < 64) ssq[tid] = 0.f;                // ordered by hgemm's first sync
    f32x4 acc[4][4];
    hgemm_bt<DIMF, 4>(Z + (size_t)b * 64 * DIMF, DIMF, W2t, DIMF, acc);
    int lane = tid & 63, w = tid >> 6;
    int qd = lane >> 4, l15 = lane & 15;
    int d = b / 3, mod = b % 3;
    float bb[4];
#pragma unroll
    for (int fn = 0; fn < 4; fn++)
        bb[fn] = b2[w * 64 + fn * 16 + l15];
#pragma unroll
    for (int fm = 0; fm < 4; fm++)
#pragma unroll
        for (int rg = 0; rg < 4; rg++) {
            int i = fm * 16 + qd * 4 + rg;       // row within 64-row band
            float* orow = outp + (size_t)(d * 64 + i) * 768 + mod * GDIM;
            float s2 = 0.f;
#pragma unroll
            for (int fn = 0; fn < 4; fn++) {
                int go = w * 64 + fn * 16 + l15;
                float vv = fmaxf(acc[fm][fn][rg] + bb[fn], 0.f);
                orow[go] = vv;
                tile[i * 256 + go] = vv;
                s2 += vv * vv;
            }
            s2 += __shfl_xor(s2, 1);
            s2 += __shfl_xor(s2, 2);
            s2 += __shfl_xor(s2, 4);
            s2 += __shfl_xor(s2, 8);
            if (l15 == 0) atomicAdd(&ssq[i], s2);
        }
    __syncthreads();
    if (tid < 64) ssq[tid] = 1.f / (sqrtf(ssq[tid]) + 1e-8f);
    __syncthreads();
    // emit bf16 normalized rows, chunk-swizzled for k9's DMA staging
#pragma unroll
    for (int it = 0; it < 8; it++) {
        int f = tid + it * 256;                  // 0..2047 chunk ids
        int row = f >> 5, c = f & 31;
        float4 xa = *(const float4*)&tile[row * 256 + c * 8];
        float4 xb = *(const float4*)&tile[row * 256 + c * 8 + 4];
        float iv = ssq[row];
        us8 o = {f2bf(xa.x * iv), f2bf(xa.y * iv), f2bf(xa.z * iv), f2bf(xa.w * iv),
                 f2bf(xb.x * iv), f2bf(xb.y * iv), f2bf(xb.z * iv), f2bf(xb.w * iv)};
        int rx = d * 64 + row;
        int slot = (c & 24) | ((c & 7) ^ (row & 7));
        *(us8*)&xnb[((size_t)mod * NROW + rx) * GDIM + slot * 8] = o;
    }
}

// ---- K9: bf16 MFMA sim, 256x256 tiles, 8 waves, global_load_lds staging.
//      NO device fences (R5 lesson: they evict shared L2 -> 3x slowdown). ----
#define TILE2 256
__global__ __launch_bounds__(512, 2) void k9_mfma(const ushort* __restrict__ xnb,
                                                  float* __restrict__ rs,
                                                  float* __restrict__ cs,
                                                  float* __restrict__ diag) {
    int cj = blockIdx.x, ci = blockIdx.y, p = blockIdx.z;
    int px = (p == 2) ? 1 : 0;
    int py = (p == 0) ? 1 : 2;
    const ushort* A = xnb + ((size_t)px * NROW + ci * TILE2) * GDIM;
    const ushort* B = xnb + ((size_t)py * NROW + cj * TILE2) * GDIM;

    __shared__ __align__(16) ushort As[TILE2 * 64];
    __shared__ __align__(16) ushort Bs[TILE2 * 64];

    const int tid = threadIdx.x;
    const int lane = tid & 63, w = tid >> 6;     // 8 waves
    const int wrow = w >> 2, wcol = w & 3;       // 2 x 4 wave grid
    const int qd = lane >> 4, l15 = lane & 15;
    const int lrow = lane >> 3, lslot = lane & 7;

    f32x4 acc[8][4] = {};

    for (int kh = 0; kh < 4; kh++) {             // BK = 64 per stage
#pragma unroll
        for (int j = 0; j < 4; j++) {
            int rr = w * 32 + j * 8 + lrow;      // per-lane global row
            __builtin_amdgcn_global_load_lds(
                (gm_us*)(A + (size_t)rr * GDIM + kh * 64 + lslot * 8),
                (lds_us*)&As[(w * 32 + j * 8) * 64], 16, 0, 0);
            __builtin_amdgcn_global_load_lds(
                (gm_us*)(B + (size_t)rr * GDIM + kh * 64 + lslot * 8),
                (lds_us*)&Bs[(w * 32 + j * 8) * 64], 16, 0, 0);
        }
        __syncthreads();
#pragma unroll
        for (int kk = 0; kk < 2; kk++) {
            bf16x8 af[8], bfv[4];
#pragma unroll
            for (int fm = 0; fm < 8; fm++) {
                int ar = wrow * 128 + fm * 16 + l15;
                af[fm] = *(const bf16x8*)&As[ar * 64 + ((kk * 4 + qd) ^ (ar & 7)) * 8];
            }
#pragma unroll
            for (int fn = 0; fn < 4; fn++) {
                int br = wcol * 64 + fn * 16 + l15;
                bfv[fn] = *(const bf16x8*)&Bs[br * 64 + ((kk * 4 + qd) ^ (br & 7)) * 8];
            }
#pragma unroll
            for (int fm = 0; fm < 8; fm++)
#pragma unroll
                for (int fn = 0; fn < 4; fn++)
                    acc[fm][fn] = __builtin_amdgcn_mfma_f32_16x16x32_bf16(
                        af[fm], bfv[fn], acc[fm][fn], 0, 0, 0);
        }
        __syncthreads();
    }

    float rloc[8][4] = {};
    float cloc[4] = {};
#pragma unroll
    for (int fm = 0; fm < 8; fm++)
#pragma unroll
        for (int fn = 0; fn < 4; fn++)
#pragma unroll
            for (int rg = 0; rg < 4; rg++) {
                float s = acc[fm][fn][rg] * INV_TAU;
                float e = __expf(s);
                rloc[fm][rg] += e;
                cloc[fn] += e;
                int grow = ci * TILE2 + wrow * 128 + fm * 16 + qd * 4 + rg;
                int gcol = cj * TILE2 + wcol * 64 + fn * 16 + l15;
                if (grow == gcol) diag[p * NROW + grow] = s;
            }
#pragma unroll
    for (int fm = 0; fm < 8; fm++)
#pragma unroll
        for (int rg = 0; rg < 4; rg++) {
            float s = rloc[fm][rg];
            s += __shfl_xor(s, 1);
            s += __shfl_xor(s, 2);
            s += __shfl_xor(s, 4);
            s += __shfl_xor(s, 8);
            if (l15 == 0)
                atomicAdd(&rs[p * NROW + ci * TILE2 + wrow * 128 + fm * 16 + qd * 4 + rg], s);
        }
#pragma unroll
    for (int fn = 0; fn < 4; fn++) {
        float s = cloc[fn];
        s += __shfl_xor(s, 16);
        s += __shfl_xor(s, 32);
        if (qd == 0)
            atomicAdd(&cs[p * NROW + cj * TILE2 + wcol * 64 + fn * 16 + l15], s);
    }
}

// ---- K10: final loss reduction ----
__global__ void k10_loss(const float* __restrict__ diag, const float* __restrict__ rs,
                         const float* __restrict__ cs, float* __restrict__ outp) {
    float acc = 0.f;
    for (int i = threadIdx.x; i < 3 * NROW; i += 256)
        acc += 2.f * diag[i] - logf(rs[i]) - logf(cs[i]);
    int lane = threadIdx.x & 63, wv = threadIdx.x >> 6;
    for (int o = 32; o; o >>= 1) acc += __shfl_down(acc, o);
    __shared__ float red[4];
    if (lane == 0) red[wv] = acc;
    __syncthreads();
    if (threadIdx.x == 0) {
        float tot = red[0] + red[1] + red[2] + red[3];
        outp[(size_t)NROW * 768] = -tot / (NROW * 6.0f);
    }
}

extern "C" void kernel_launch(void* const* d_in, const int* in_sizes, int n_in,
                              void* d_out, int out_size, void* d_ws, size_t ws_size,
                              hipStream_t stream) {
    const float* t   = (const float*)d_in[0];
    const float* a   = (const float*)d_in[1];
    const float* v   = (const float*)d_in[2];
    const float* Wfc = (const float*)d_in[3];
    const float* bfc = (const float*)d_in[4];
    const float* Wh  = (const float*)d_in[5];
    const float* bh  = (const float*)d_in[6];
    float* outp = (float*)d_out;
    float* ws = (float*)d_ws;

    // workspace layout (floats); all offsets 16B-aligned
    float* sq    = ws;                       // 12288
    float* d2F   = sq + 12288;               // 2359296 (dead after k2 -> xnb)
    float* HbTF  = d2F + 2359296;            // 1179648 (fp16 12288x192)
    float* HbTdF = HbTF + 1179648;           // 1179648 (contiguous for zeroing)
    float* degV  = HbTdF + 1179648;          // 12288
    float* feathF= degV + 12288;             // 3145728 (fp16; dead after k1 -> Z)
    float* featlF= feathF + 3145728;         // 3145728 (fp16; dead after k1 -> S)
    float* featTF= featlF + 3145728;         // 3145728 (fp16 64x512x192)
    float* WfchF = featTF + 3145728;         // 65536   (fp16 512x256)
    float* WhTF  = WfchF + 65536;            // 32768   (fp16 256x256)
    float* W2tF  = WhTF + 32768;             // 65536   (fp16 256x512)
    float* b2    = W2tF + 65536;             // 256
    float* rs    = b2 + 256;                 // 12288
    float* cs    = rs + 12288;               // 12288
    float* diag  = cs + 12288;               // 12288

    _Float16* HbT   = (_Float16*)HbTF;
    _Float16* HbTd  = (_Float16*)HbTdF;
    _Float16* feath = (_Float16*)feathF;
    _Float16* featl = (_Float16*)featlF;
    _Float16* featT = (_Float16*)featTF;
    _Float16* Wfch  = (_Float16*)WfchF;
    _Float16* WhT   = (_Float16*)WhTF;
    _Float16* W2t   = (_Float16*)W2tF;
    _Float16* S     = (_Float16*)featlF;     // overlays featl (dead after k1)
    _Float16* Z     = (_Float16*)feathF;     // overlays feath (dead after k1)
    ushort*   xnb   = (ushort*)d2F;          // bf16[3][4096][256] (swizzled)

    kprep  <<<13296, 256, 0, stream>>>(t, a, v, Wfc, Wh, feath, featl, featT,
                                       Wfch, WhT, sq, rs, cs, degV, HbT);
    kW     <<<9, 256, 0, stream>>>(WhT, Wfch, bfc, bh, Wh, W2t, b2);
    k1_d2  <<<dim3(3, 64), 192, 0, stream>>>(feath, featl, sq, d2F);
    k2_topk<<<3072, 256, 0, stream>>>(d2F, HbT, HbTd, degV);
    kM     <<<dim3(3, 64), 192, 0, stream>>>(HbT, HbTd, S);
    kZ     <<<dim3(6, 64), 256, 0, stream>>>(S, featT, degV, Z);
    kO     <<<192, 256, 0, stream>>>(Z, W2t, b2, outp, xnb);
    k9_mfma<<<dim3(16, 16, 3), 512, 0, stream>>>(xnb, rs, cs, diag);
    k10_loss<<<1, 256, 0, stream>>>(diag, rs, cs, outp);
}